// Round 3
// baseline (255.036 us; speedup 1.0000x reference)
//
#include <hip/hip_runtime.h>
#include <math.h>

#define B_ 16
#define C_ 384
#define N_ 1024
#define K_ 9

typedef _Float16 f16x8 __attribute__((ext_vector_type(8)));
typedef _Float16 f16x4 __attribute__((ext_vector_type(4)));
typedef float f32x4 __attribute__((ext_vector_type(4)));
typedef unsigned long long u64;

__device__ __forceinline__ void gld_lds16(const void* g, void* l) {
  __builtin_amdgcn_global_load_lds((const __attribute__((address_space(1))) void*)g,
                                   (__attribute__((address_space(3))) void*)l, 16, 0, 0);
}

// ---------------- transpose + fp16 split: x[b][c][n] -> xhT/xlT [b][n][c] ----------------
__global__ void k_cvt(const float* __restrict__ x, ushort* __restrict__ xhT,
                      ushort* __restrict__ xlT) {
  const int bid = blockIdx.x;  // ((b*16 + nt)*12 + ct)
  const int ct = bid % 12;
  const int nt = (bid / 12) & 15;
  const int b = bid / 192;
  const int c0 = ct * 32, n0 = nt * 64;
  __shared__ float ld[32 * 65];
  const int t = threadIdx.x;
  {
    const int c = t >> 3, n8 = (t & 7) * 8;
    const float* src = x + ((size_t)(b * C_ + c0 + c) * N_ + n0 + n8);
    float4 v0 = *(const float4*)src;
    float4 v1 = *(const float4*)(src + 4);
    float vv[8] = {v0.x, v0.y, v0.z, v0.w, v1.x, v1.y, v1.z, v1.w};
#pragma unroll
    for (int j = 0; j < 8; ++j) ld[c * 65 + n8 + j] = vv[j];
  }
  __syncthreads();
  {
    const int n = t >> 2, c8 = (t & 3) * 8;
    f16x8 hv, lv;
#pragma unroll
    for (int j = 0; j < 8; ++j) {
      float v = ld[(c8 + j) * 65 + n];
      _Float16 h = (_Float16)v;
      _Float16 l = (_Float16)(v - (float)h);
      hv[j] = h;
      lv[j] = l;
    }
    const size_t off = (size_t)(b * N_ + n0 + n) * C_ + c0 + c8;
    *(f16x8*)(xhT + off) = hv;
    *(f16x8*)(xlT + off) = lv;
  }
}

// ---------------- Wg -> WgH/WgL ----------------
__global__ void k_cvtw(const float* __restrict__ Wg, ushort* __restrict__ WgH,
                       ushort* __restrict__ WgL) {
  const int i = (blockIdx.x * 256 + threadIdx.x) * 4;  // 144 blocks
  float4 v = *(const float4*)(Wg + i);
  float vv[4] = {v.x, v.y, v.z, v.w};
  f16x4 hv, lv;
#pragma unroll
  for (int j = 0; j < 4; ++j) {
    _Float16 h = (_Float16)vv[j];
    hv[j] = h;
    lv[j] = (_Float16)(vv[j] - (float)h);
  }
  *(f16x4*)(WgH + i) = hv;
  *(f16x4*)(WgL + i) = lv;
}

// ---------------- sq[b][n] = sum_c x[b][c][n]^2 (fp64 accum) ----------------
__global__ void k_sq(const float* __restrict__ x, float* __restrict__ sq) {
  const int idx = blockIdx.x * blockDim.x + threadIdx.x;
  const int b = idx >> 10, n = idx & 1023;
  const float* xb = x + (size_t)b * C_ * N_ + n;
  double s = 0.0;
#pragma unroll 4
  for (int c = 0; c < C_; ++c) {
    float v = xb[(size_t)c * N_];
    s = fma((double)v, (double)v, s);
  }
  sq[idx] = (float)s;
}

// ---------------- MFMA Gram -> D[b_local][n][m], symmetric tiles only ----------------
// Per batch: 36 upper-triangular 128x128 tiles (rt<=mt); off-diag tiles mirror-write
// D[m][n] as float4. MFMA work -44% vs full grid.
// LDS halved to 2x16KB (Ah/Bh only); Al/Bl fragments are consumed once per K-step so
// they're read DIRECTLY from global (XCD-L2-resident), software-prefetched 1 K-step
// ahead. ds_read_b128/iter 16->8; occupancy 2->3 blocks/CU.
__global__ __launch_bounds__(256, 3) void k_gram(const ushort* __restrict__ xhT,
                                                 const ushort* __restrict__ xlT,
                                                 const float* __restrict__ sq,
                                                 float* __restrict__ D, int base_b, int nb) {
  const int bid = blockIdx.x;
  int b_local, pid;
  if (nb >= 8) {
    const int xcd = bid & 7, j = bid >> 3, grp = nb >> 3;
    b_local = xcd * grp + j / 36;
    pid = j % 36;
  } else {
    b_local = bid / 36;
    pid = bid % 36;
  }
  const int b = base_b + b_local;
  // triangular tile map: pid -> (rt, mt), rt <= mt
  int rt = 0, off = 0;
  while (pid >= off + (8 - rt)) {
    off += 8 - rt;
    ++rt;
  }
  const int mt = rt + (pid - off);
  const int n0 = rt * 128, m0 = mt * 128;

  __shared__ alignas(16) char sm[2][16384];  // per buf: Ah@0 Bh@8192
  const int t = threadIdx.x;
  const int lane = t & 63, wid = t >> 6, quad = lane >> 4, lrow = lane & 15;
  const int wr = wid >> 1, wc = wid & 1;
  const int lrow4 = lane >> 2, lpos = lane & 3;

  const char* ah_src = (const char*)xhT + (size_t)(b * N_ + n0) * 768;
  const char* bh_src = (const char*)xhT + (size_t)(b * N_ + m0) * 768;
  const char* al_src = (const char*)xlT + (size_t)(b * N_ + n0) * 768;
  const char* bl_src = (const char*)xlT + (size_t)(b * N_ + m0) * 768;

  f32x4 acc[4][4];
#pragma unroll
  for (int mi = 0; mi < 4; ++mi)
#pragma unroll
    for (int ni = 0; ni < 4; ++ni) acc[mi][ni] = (f32x4){0.f, 0.f, 0.f, 0.f};

  // staging: wid0/1 -> Ah halves, wid2/3 -> Bh halves (4 gld_lds16 each)
  const int arr = wid >> 1, half = wid & 1;
  const char* st_src = arr ? bh_src : ah_src;
  auto stage = [&](int it) {
    char* dst = sm[it & 1] + arr * 8192 + half * 4096;
    const int ktB = it * 64;
#pragma unroll
    for (int i = 0; i < 4; ++i) {
      const int row = half * 64 + i * 16 + lrow4;
      const int swz = lpos ^ ((row >> 1) & 3);
      gld_lds16(st_src + (size_t)row * 768 + ktB + swz * 16, dst + i * 1024 + lane * 16);
    }
  };

  f16x8 alc[4], blc[4], aln[4], bln[4];
  auto load_l = [&](int it, f16x8* a, f16x8* bl_) {
    const int ktB = it * 64;
#pragma unroll
    for (int mi = 0; mi < 4; ++mi) {
      const int row = wr * 64 + mi * 16 + lrow;
      a[mi] = *(const f16x8*)(al_src + (size_t)row * 768 + ktB + quad * 16);
    }
#pragma unroll
    for (int ni = 0; ni < 4; ++ni) {
      const int row = wc * 64 + ni * 16 + lrow;
      bl_[ni] = *(const f16x8*)(bl_src + (size_t)row * 768 + ktB + quad * 16);
    }
  };

  stage(0);
  load_l(0, alc, blc);
  for (int it = 0; it < 12; ++it) {
    __syncthreads();
    if (it < 11) {
      stage(it + 1);
      load_l(it + 1, aln, bln);
    }
    const char* smb = sm[it & 1];
    f16x8 ah[4];
#pragma unroll
    for (int mi = 0; mi < 4; ++mi) {
      const int row = wr * 64 + mi * 16 + lrow;
      ah[mi] = *(const f16x8*)(smb + row * 64 + (quad ^ ((row >> 1) & 3)) * 16);
    }
#pragma unroll
    for (int ni = 0; ni < 4; ++ni) {
      const int row = wc * 64 + ni * 16 + lrow;
      f16x8 bh = *(const f16x8*)(smb + 8192 + row * 64 + (quad ^ ((row >> 1) & 3)) * 16);
#pragma unroll
      for (int mi = 0; mi < 4; ++mi) {
        acc[mi][ni] = __builtin_amdgcn_mfma_f32_16x16x32_f16(ah[mi], bh, acc[mi][ni], 0, 0, 0);
        acc[mi][ni] = __builtin_amdgcn_mfma_f32_16x16x32_f16(alc[mi], bh, acc[mi][ni], 0, 0, 0);
        acc[mi][ni] = __builtin_amdgcn_mfma_f32_16x16x32_f16(ah[mi], blc[ni], acc[mi][ni], 0, 0, 0);
      }
    }
    if (it < 11) {
#pragma unroll
      for (int i = 0; i < 4; ++i) {
        alc[i] = aln[i];
        blc[i] = bln[i];
      }
    }
  }

  // epilogue: d = (sq_n + sq_m) - 2g, diag -> FLT_MAX; normal store + mirror float4 store
  const float* sqb = sq + b * N_;
  float sqm[4];
#pragma unroll
  for (int ni = 0; ni < 4; ++ni) sqm[ni] = sqb[m0 + wc * 64 + ni * 16 + lrow];
  float sqn_[4][4];
#pragma unroll
  for (int mi = 0; mi < 4; ++mi)
#pragma unroll
    for (int r = 0; r < 4; ++r) sqn_[mi][r] = sqb[n0 + wr * 64 + mi * 16 + quad * 4 + r];

  float* Db = D + (size_t)b_local * N_ * N_;
  const bool mirror = (rt != mt);
#pragma unroll
  for (int mi = 0; mi < 4; ++mi)
#pragma unroll
    for (int ni = 0; ni < 4; ++ni) {
      float dv[4];
#pragma unroll
      for (int r = 0; r < 4; ++r) {
        const int ng = n0 + wr * 64 + mi * 16 + quad * 4 + r;
        const int mg = m0 + wc * 64 + ni * 16 + lrow;
        float d = fmaf(-2.f, acc[mi][ni][r], sqn_[mi][r] + sqm[ni]);
        if (ng == mg) d = 3.402823466e38f;
        Db[(size_t)ng * N_ + mg] = d;
        dv[r] = d;
      }
      if (mirror) {
        const int mg = m0 + wc * 64 + ni * 16 + lrow;
        const int ngb = n0 + wr * 64 + mi * 16 + quad * 4;
        float4 f4 = {dv[0], dv[1], dv[2], dv[3]};
        *(float4*)&Db[(size_t)mg * N_ + ngb] = f4;
      }
    }
}

// ---------------- top-9 over D row: 2 rows/wave, 32 lanes/row, f32 value keys ----------
// Selection on VALUES only (f32 CEs are 2 ops vs ~5 for u64 lex keys), then a cheap
// index-recovery pass. Neighbor ORDER is irrelevant downstream (segment-sum), so we only
// need the correct SET: all cols with d < v9, plus lowest-index cols with d == v9 to fill
// to 9 — exactly lax.top_k's stable tie semantics.
__device__ __forceinline__ void ce2f(float& a, float& b) {
  float lo = fminf(a, b), hi = fmaxf(a, b);
  a = lo;
  b = hi;
}

__global__ __launch_bounds__(256) void k_scan(const float* __restrict__ D,
                                              int* __restrict__ nbr, int base_node) {
  const int t = threadIdx.x;
  const int lane = t & 63, wid = t >> 6;
  const int g = lane >> 5;   // row within wave (0..1)
  const int ll = lane & 31;  // lane within 32-lane row group
  const int nl = blockIdx.x * 8 + wid * 2 + g;
  const float* row = D + (size_t)nl * N_ + ll * 32;
  // 32 contiguous columns per lane (kept in regs for the index-recovery pass)
  float v[32];
#pragma unroll
  for (int i = 0; i < 8; ++i) {
    float4 q = *(const float4*)(row + i * 4);
    v[i * 4 + 0] = q.x;
    v[i * 4 + 1] = q.y;
    v[i * 4 + 2] = q.z;
    v[i * 4 + 3] = q.w;
  }
  // per-lane sorted top-9 of its 32 values
  float key[9];
#pragma unroll
  for (int k = 0; k < 9; ++k) key[k] = 3.402823466e38f;
#pragma unroll
  for (int j = 0; j < 32; ++j) {
    key[8] = fminf(key[8], v[j]);
#pragma unroll
    for (int s = 8; s >= 1; --s) ce2f(key[s - 1], key[s]);
  }
  // butterfly merge across the 32-lane group: m[i]=min(a[i],b[8-i]) is bitonic; 13-CE cleanup
#pragma unroll
  for (int lvl = 1; lvl < 32; lvl <<= 1) {
    float pk[9];
#pragma unroll
    for (int k = 0; k < 9; ++k) pk[k] = __shfl_xor(key[k], lvl, 64);
    float m[9];
#pragma unroll
    for (int k = 0; k < 9; ++k) m[k] = fminf(key[k], pk[8 - k]);
    ce2f(m[0], m[8]);
    ce2f(m[1], m[5]); ce2f(m[2], m[6]); ce2f(m[3], m[7]); ce2f(m[4], m[8]);
    ce2f(m[1], m[3]); ce2f(m[2], m[4]); ce2f(m[5], m[7]); ce2f(m[6], m[8]);
    ce2f(m[1], m[2]); ce2f(m[3], m[4]); ce2f(m[5], m[6]); ce2f(m[7], m[8]);
#pragma unroll
    for (int k = 0; k < 9; ++k) key[k] = m[k];
  }
  // all 32 lanes now hold the row's sorted top-9 values
  const float v9 = key[8];
  int c_lt = 0;  // global count of d < v9
#pragma unroll
  for (int k = 0; k < 8; ++k) c_lt += (key[k] < v9) ? 1 : 0;

  unsigned lt_mask = 0u, eq_mask = 0u;
#pragma unroll
  for (int j = 0; j < 32; ++j) {
    lt_mask |= (v[j] < v9) ? (1u << j) : 0u;
    eq_mask |= (v[j] == v9) ? (1u << j) : 0u;
  }
  const int lt_cnt = __popc(lt_mask), eq_cnt = __popc(eq_mask);
  // exclusive prefix over the 32-lane group in ascending-index order
  int packed = lt_cnt | (eq_cnt << 16);
  int run = packed;
#pragma unroll
  for (int off = 1; off < 32; off <<= 1) {
    int q = __shfl_up(run, off, 32);
    if (ll >= off) run += q;
  }
  const int pref = run - packed;
  const int lt_pref = pref & 0xFFFF, eq_pref = pref >> 16;

  int* np = nbr + (size_t)(base_node + nl) * K_;
  int slot = lt_pref;
  unsigned m = lt_mask;
  while (m) {
    int j = __builtin_ctz(m);
    m &= m - 1;
    np[slot++] = ll * 32 + j;
  }
  slot = c_lt + eq_pref;
  m = eq_mask;
  while (m && slot < 9) {
    int j = __builtin_ctz(m);
    m &= m - 1;
    np[slot++] = ll * 32 + j;
  }
}

// ---------------- MFMA xw[b][co][n]: A=Wg(h/l), B=xT(h/l), dbuf staging ----------------
// XCD swizzle: the 6 ct-blocks sharing one (b,nt) B-tile (196KB of xhT/xlT) get bids
// congruent mod 8 -> same XCD -> B-tile fetched once into that XCD's L2.
__global__ __launch_bounds__(256, 3) void k_xw(const ushort* __restrict__ xhT,
                                               const ushort* __restrict__ xlT,
                                               const ushort* __restrict__ WgH,
                                               const ushort* __restrict__ WgL,
                                               float* __restrict__ xw) {
  const int bid = blockIdx.x;
  const int xcd = bid & 7, j = bid >> 3;   // 96 blocks per XCD
  const int pair = xcd * 16 + j / 6;       // (b,nt) pair; 6 consecutive j share it
  const int ct = j % 6;
  const int b = pair >> 3, nt = pair & 7;
  const int co0 = ct * 64, n0 = nt * 128;
  __shared__ alignas(16) char sm[2][24576];  // per buf: Ah@0 Al@4096 Bh@8192 Bl@16384
  const int t = threadIdx.x;
  const int lane = t & 63, wid = t >> 6, quad = lane >> 4, lrow = lane & 15;
  const int wr = wid >> 1, wc = wid & 1;
  const int lrow4 = lane >> 2, lpos = lane & 3;

  f32x4 acc[2][4];
#pragma unroll
  for (int mi = 0; mi < 2; ++mi)
#pragma unroll
    for (int ni = 0; ni < 4; ++ni) acc[mi][ni] = (f32x4){0.f, 0.f, 0.f, 0.f};

  const char* asrc[2] = {(const char*)(WgH + (size_t)co0 * C_),
                         (const char*)(WgL + (size_t)co0 * C_)};
  const char* bsrc[2] = {(const char*)(xhT + (size_t)(b * N_ + n0) * C_),
                         (const char*)(xlT + (size_t)(b * N_ + n0) * C_)};

  auto stage = [&](int it) {
    char* dst = sm[it & 1];
    const int ktB = it * 64;
#pragma unroll
    for (int i = 0; i < 6; ++i) {
      const int c = wid * 6 + i;
      const char* src;
      int base, row;
      if (c < 8) {
        const int arr = c >> 2, sub = c & 3;
        src = asrc[arr];
        base = arr * 4096 + sub * 1024;
        row = sub * 16 + lrow4;
      } else {
        const int cc = c - 8, arr = cc >> 3, sub = cc & 7;
        src = bsrc[arr];
        base = 8192 + arr * 8192 + sub * 1024;
        row = sub * 16 + lrow4;
      }
      const int swz = lpos ^ ((row >> 1) & 3);
      gld_lds16(src + (size_t)row * 768 + ktB + swz * 16, dst + base + lane * 16);
    }
  };

  stage(0);
  for (int it = 0; it < 12; ++it) {
    __syncthreads();
    if (it < 11) stage(it + 1);
    const char* smb = sm[it & 1];
    f16x8 bh[4], bl[4];
#pragma unroll
    for (int ni = 0; ni < 4; ++ni) {
      const int row = wr * 64 + ni * 16 + lrow;
      const int off = row * 64 + (quad ^ ((row >> 1) & 3)) * 16;
      bh[ni] = *(const f16x8*)(smb + 8192 + off);
      bl[ni] = *(const f16x8*)(smb + 16384 + off);
    }
#pragma unroll
    for (int mi = 0; mi < 2; ++mi) {
      const int row = wc * 32 + mi * 16 + lrow;
      const int off = row * 64 + (quad ^ ((row >> 1) & 3)) * 16;
      f16x8 ah = *(const f16x8*)(smb + off);
      f16x8 al = *(const f16x8*)(smb + 4096 + off);
#pragma unroll
      for (int ni = 0; ni < 4; ++ni) {
        acc[mi][ni] = __builtin_amdgcn_mfma_f32_16x16x32_f16(ah, bh[ni], acc[mi][ni], 0, 0, 0);
        acc[mi][ni] = __builtin_amdgcn_mfma_f32_16x16x32_f16(al, bh[ni], acc[mi][ni], 0, 0, 0);
        acc[mi][ni] = __builtin_amdgcn_mfma_f32_16x16x32_f16(ah, bl[ni], acc[mi][ni], 0, 0, 0);
      }
    }
  }
#pragma unroll
  for (int mi = 0; mi < 2; ++mi)
#pragma unroll
    for (int ni = 0; ni < 4; ++ni)
#pragma unroll
      for (int r = 0; r < 4; ++r) {
        const int c_g = co0 + wc * 32 + mi * 16 + quad * 4 + r;
        const int n_g = n0 + wr * 64 + ni * 16 + lrow;
        xw[((size_t)b * C_ + c_g) * N_ + n_g] = acc[mi][ni][r];
      }
}

// ---------------- aggregate (deg==10 uniformly) + BN partial stats ----------------
// 8 channels per block: nbr staged once per 8 channels, the 9 neighbor indices read
// once and reused 8x.
__global__ __launch_bounds__(256) void k_agg(const float* __restrict__ xw,
                                             const int* __restrict__ nbr,
                                             const float* __restrict__ bg,
                                             float* __restrict__ out,
                                             float* __restrict__ stats) {
  const int ct = blockIdx.x % (C_ / 8);  // 48
  const int b = blockIdx.x / (C_ / 8);
  const int c0 = ct * 8;
  __shared__ alignas(16) int nb_l[N_ * K_];       // 36864 B
  __shared__ alignas(16) float row_l[8][N_ + 4];  // 32896 B
  __shared__ float red[2][8][4];
  const int tid = threadIdx.x;
  const int4* gp = (const int4*)(nbr + (size_t)b * N_ * K_);
  int4* lp = (int4*)nb_l;
  for (int t = tid; t < N_ * K_ / 4; t += 256) lp[t] = gp[t];
  for (int t = tid; t < 8 * (N_ / 4); t += 256) {
    const int j = t >> 8, n4 = t & 255;  // N_/4 = 256
    float4 v = ((const float4*)(xw + ((size_t)(b * C_ + c0 + j)) * N_))[n4];
    *(float4*)&row_l[j][n4 * 4] = v;
  }
  __syncthreads();
  float bgc[8];
#pragma unroll
  for (int j = 0; j < 8; ++j) bgc[j] = bg[c0 + j];
  float s1[8], s2[8];
#pragma unroll
  for (int j = 0; j < 8; ++j) {
    s1[j] = 0.f;
    s2[j] = 0.f;
  }
  float* outb = out + ((size_t)b * C_ + c0) * N_;
#pragma unroll
  for (int s = 0; s < 4; ++s) {
    const int n = tid + 256 * s;
    const int* nn_ = &nb_l[n * K_];
    int idx[K_];
#pragma unroll
    for (int k = 0; k < K_; ++k) idx[k] = nn_[k];
    float a[8];
#pragma unroll
    for (int j = 0; j < 8; ++j) a[j] = row_l[j][n];
#pragma unroll
    for (int k = 0; k < K_; ++k) {
      const int m = idx[k];
#pragma unroll
      for (int j = 0; j < 8; ++j) a[j] += row_l[j][m];
    }
#pragma unroll
    for (int j = 0; j < 8; ++j) {
      float y = fmaf(a[j], 0.099999994f, bgc[j]);
      outb[(size_t)j * N_ + n] = y;
      s1[j] += y;
      s2[j] = fmaf(y, y, s2[j]);
    }
  }
#pragma unroll
  for (int off = 32; off > 0; off >>= 1)
#pragma unroll
    for (int j = 0; j < 8; ++j) {
      s1[j] += __shfl_down(s1[j], off, 64);
      s2[j] += __shfl_down(s2[j], off, 64);
    }
  const int lane = tid & 63, wid = tid >> 6;
  if (lane == 0)
#pragma unroll
    for (int j = 0; j < 8; ++j) {
      red[0][j][wid] = s1[j];
      red[1][j][wid] = s2[j];
    }
  __syncthreads();
  if (tid < 16) {
    const int j = tid & 7, which = tid >> 3;
    float v = red[which][j][0] + red[which][j][1] + red[which][j][2] + red[which][j][3];
    atomicAdd(&stats[which * C_ + c0 + j], v);
  }
}

// ---------------- BN (batch stats) + tanh-GELU + residual ----------------
__global__ void k_bn(const float* __restrict__ x, const float* __restrict__ gamma,
                     const float* __restrict__ beta, const float* __restrict__ stats,
                     float* __restrict__ out) {
  const int f = blockIdx.x * blockDim.x + threadIdx.x;
  const int e = f * 4;
  const int c = (e >> 10) % C_;
  const float inv = 1.f / 16384.f;
  const float mu = stats[c] * inv;
  const float var = fmaf(-mu, mu, stats[C_ + c] * inv);
  const float sc = gamma[c] * rsqrtf(var + 1e-5f);
  const float sh = fmaf(-mu, sc, beta[c]);
  float4 y = ((const float4*)out)[f];
  float4 xv = ((const float4*)x)[f];
  auto gl = [](float z) {
    float z3 = z * z * z;
    float t = 0.7978845608028654f * fmaf(0.044715f, z3, z);
    float th = tanhf(t);
    return 0.5f * z * (1.f + th);
  };
  float4 o;
  o.x = gl(fmaf(y.x, sc, sh)) + xv.x;
  o.y = gl(fmaf(y.y, sc, sh)) + xv.y;
  o.z = gl(fmaf(y.z, sc, sh)) + xv.z;
  o.w = gl(fmaf(y.w, sc, sh)) + xv.w;
  ((float4*)out)[f] = o;
}

extern "C" void kernel_launch(void* const* d_in, const int* in_sizes, int n_in,
                              void* d_out, int out_size, void* d_ws, size_t ws_size,
                              hipStream_t stream) {
  const float* x = (const float*)d_in[0];
  const float* Wg = (const float*)d_in[1];
  const float* bg = (const float*)d_in[2];
  const float* gamma = (const float*)d_in[3];
  const float* beta = (const float*)d_in[4];
  float* out = (float*)d_out;

  int nb;
  if (ws_size >= 94000000) nb = 16;
  else if (ws_size >= 60500000) nb = 8;
  else nb = 4;

  char* ws = (char*)d_ws;
  ushort* xhT = (ushort*)ws;                  // @0          12,582,912
  ushort* xlT = (ushort*)(ws + 12582912);     //             12,582,912
  ushort* WgH = (ushort*)(ws + 25165824);     //                294,912
  ushort* WgL = (ushort*)(ws + 25460736);     //                294,912
  float* sq = (float*)(ws + 25755648);        //                 65,536
  float* Dbuf = (float*)(ws + 25821184);      // nb*4,194,304
  float* xw = (float*)(ws + 25821184);        // overlays Dbuf (Dbuf dead after scans)
  size_t dreg = (size_t)nb * 4194304;
  if (dreg < 25165824) dreg = 25165824;       // xw needs 25.17 MB
  int* nbr = (int*)(ws + 25821184 + dreg);    //                589,824
  float* stats = (float*)(ws + 25821184 + dreg + 589824);  //     3,072

  hipMemsetAsync(stats, 0, 2 * C_ * sizeof(float), stream);
  k_cvt<<<3072, 256, 0, stream>>>(x, xhT, xlT);
  k_cvtw<<<144, 256, 0, stream>>>(Wg, WgH, WgL);
  k_sq<<<64, 256, 0, stream>>>(x, sq);
  for (int r = 0; r < B_ / nb; ++r) {
    k_gram<<<nb * 36, 256, 0, stream>>>(xhT, xlT, sq, Dbuf, r * nb, nb);
    k_scan<<<nb * 128, 256, 0, stream>>>(Dbuf, nbr, r * nb * N_);
  }
  k_xw<<<768, 256, 0, stream>>>(xhT, xlT, WgH, WgL, xw);
  k_agg<<<B_ * (C_ / 8), 256, 0, stream>>>(xw, nbr, bg, out, stats);
  k_bn<<<6144, 256, 0, stream>>>(x, gamma, beta, stats, out);
}

// Round 4
// 235.529 us; speedup vs baseline: 1.0828x; 1.0828x over previous
//
#include <hip/hip_runtime.h>
#include <math.h>

#define B_ 16
#define C_ 384
#define N_ 1024
#define K_ 9

typedef _Float16 f16x8 __attribute__((ext_vector_type(8)));
typedef _Float16 f16x4 __attribute__((ext_vector_type(4)));
typedef float f32x4 __attribute__((ext_vector_type(4)));
typedef unsigned long long u64;

__device__ __forceinline__ void gld_lds16(const void* g, void* l) {
  __builtin_amdgcn_global_load_lds((const __attribute__((address_space(1))) void*)g,
                                   (__attribute__((address_space(3))) void*)l, 16, 0, 0);
}

// ---------------- transpose + fp16 split: x[b][c][n] -> xhT/xlT [b][n][c] ----------------
__global__ void k_cvt(const float* __restrict__ x, ushort* __restrict__ xhT,
                      ushort* __restrict__ xlT) {
  const int bid = blockIdx.x;  // ((b*16 + nt)*12 + ct)
  const int ct = bid % 12;
  const int nt = (bid / 12) & 15;
  const int b = bid / 192;
  const int c0 = ct * 32, n0 = nt * 64;
  __shared__ float ld[32 * 65];
  const int t = threadIdx.x;
  {
    const int c = t >> 3, n8 = (t & 7) * 8;
    const float* src = x + ((size_t)(b * C_ + c0 + c) * N_ + n0 + n8);
    float4 v0 = *(const float4*)src;
    float4 v1 = *(const float4*)(src + 4);
    float vv[8] = {v0.x, v0.y, v0.z, v0.w, v1.x, v1.y, v1.z, v1.w};
#pragma unroll
    for (int j = 0; j < 8; ++j) ld[c * 65 + n8 + j] = vv[j];
  }
  __syncthreads();
  {
    const int n = t >> 2, c8 = (t & 3) * 8;
    f16x8 hv, lv;
#pragma unroll
    for (int j = 0; j < 8; ++j) {
      float v = ld[(c8 + j) * 65 + n];
      _Float16 h = (_Float16)v;
      _Float16 l = (_Float16)(v - (float)h);
      hv[j] = h;
      lv[j] = l;
    }
    const size_t off = (size_t)(b * N_ + n0 + n) * C_ + c0 + c8;
    *(f16x8*)(xhT + off) = hv;
    *(f16x8*)(xlT + off) = lv;
  }
}

// ---------------- Wg -> WgH/WgL ----------------
__global__ void k_cvtw(const float* __restrict__ Wg, ushort* __restrict__ WgH,
                       ushort* __restrict__ WgL) {
  const int i = (blockIdx.x * 256 + threadIdx.x) * 4;  // 144 blocks
  float4 v = *(const float4*)(Wg + i);
  float vv[4] = {v.x, v.y, v.z, v.w};
  f16x4 hv, lv;
#pragma unroll
  for (int j = 0; j < 4; ++j) {
    _Float16 h = (_Float16)vv[j];
    hv[j] = h;
    lv[j] = (_Float16)(vv[j] - (float)h);
  }
  *(f16x4*)(WgH + i) = hv;
  *(f16x4*)(WgL + i) = lv;
}

// ---------------- sq pass 1: partial sums over 24-channel chunks (fp64) ----------------
// grid 1024: bid -> (b, q, nt); thread n. Coalesced along n; 4x the CU coverage of the
// old single-pass kernel.
__global__ void k_sq1(const float* __restrict__ x, double* __restrict__ part) {
  const int bid = blockIdx.x;
  const int b = bid >> 6, q = (bid >> 2) & 15, nt = bid & 3;
  const int n = nt * 256 + threadIdx.x;
  const float* xb = x + ((size_t)b * C_ + q * 24) * N_ + n;
  double s = 0.0;
#pragma unroll 4
  for (int c = 0; c < 24; ++c) {
    float v = xb[(size_t)c * N_];
    s = fma((double)v, (double)v, s);
  }
  part[((size_t)b * 16 + q) * N_ + n] = s;
}

// ---------------- sq pass 2: deterministic reduce of 16 partials ----------------
__global__ void k_sq2(const double* __restrict__ part, float* __restrict__ sq) {
  const int idx = blockIdx.x * blockDim.x + threadIdx.x;
  const int b = idx >> 10, n = idx & 1023;
  const double* p = part + (size_t)b * 16 * N_ + n;
  double s = 0.0;
#pragma unroll
  for (int q = 0; q < 16; ++q) s += p[(size_t)q * N_];
  sq[idx] = (float)s;
}

// ---------------- MFMA Gram -> D[b_local][n][m] (single-buffer, 4 blocks/CU) ----------
// grid nb*64, full 64-tile grid. XCD swizzle (nb>=8): batch group = bid&7 -> the 1.5MB
// batch working set is XCD-L2-resident.
// SINGLE 32KB LDS buffer (Ah@0 Al@8192 Bh@16384 Bl@24576), stage->barrier->compute->
// barrier. The exposed stage latency and the end-of-block store drain are hidden by
// the 3 OTHER resident blocks (4 blocks/CU at 32KB LDS, vs 2 with the 64KB dbuf):
// cross-block phase drift lets MFMA / LDS / VMEM pipes co-issue instead of lockstep.
__global__ __launch_bounds__(256, 4) void k_gram(const ushort* __restrict__ xhT,
                                                 const ushort* __restrict__ xlT,
                                                 const float* __restrict__ sq,
                                                 float* __restrict__ D, int base_b, int nb) {
  const int bid = blockIdx.x;
  int b_local, pid;
  if (nb >= 8) {
    const int xcd = bid & 7, j = bid >> 3, grp = nb >> 3;
    b_local = xcd * grp + (j >> 6);
    pid = j & 63;
  } else {
    b_local = bid >> 6;
    pid = bid & 63;
  }
  const int b = base_b + b_local;
  const int rt = pid >> 3, mt = pid & 7;
  const int n0 = rt * 128, m0 = mt * 128;

  __shared__ alignas(16) char sm[32768];
  const int t = threadIdx.x;
  const int lane = t & 63, wid = t >> 6, quad = lane >> 4, lrow = lane & 15;
  const int wr = wid >> 1, wc = wid & 1;
  const int lrow4 = lane >> 2, lpos = lane & 3;

  // wave -> array it stages: 0:Ah(n0,h) 1:Al(n0,l) 2:Bh(m0,h) 3:Bl(m0,l)
  const char* src = (const char*)((wid & 1) ? xlT : xhT) +
                    (size_t)(b * N_ + ((wid >> 1) ? m0 : n0)) * C_ * 2;

  f32x4 acc[4][4];
#pragma unroll
  for (int mi = 0; mi < 4; ++mi)
#pragma unroll
    for (int ni = 0; ni < 4; ++ni) acc[mi][ni] = (f32x4){0.f, 0.f, 0.f, 0.f};

  for (int it = 0; it < 12; ++it) {
    {  // stage K-step it into the single buffer
      char* dst = sm + wid * 8192;
      const int ktB = it * 64;
#pragma unroll
      for (int i = 0; i < 8; ++i) {
        const int row = i * 16 + lrow4;
        const int swz = lpos ^ ((row >> 1) & 3);
        gld_lds16(src + (size_t)row * 768 + ktB + swz * 16, dst + i * 1024 + lane * 16);
      }
    }
    __syncthreads();  // vmcnt(0) drain: buffer valid for all waves
    f16x8 ah[4], al[4];
#pragma unroll
    for (int mi = 0; mi < 4; ++mi) {
      const int row = wr * 64 + mi * 16 + lrow;
      const int off = row * 64 + (quad ^ ((row >> 1) & 3)) * 16;
      ah[mi] = *(const f16x8*)(sm + off);
      al[mi] = *(const f16x8*)(sm + 8192 + off);
    }
#pragma unroll
    for (int ni = 0; ni < 4; ++ni) {
      const int row = wc * 64 + ni * 16 + lrow;
      const int off = row * 64 + (quad ^ ((row >> 1) & 3)) * 16;
      f16x8 bh = *(const f16x8*)(sm + 16384 + off);
      f16x8 bl = *(const f16x8*)(sm + 24576 + off);
#pragma unroll
      for (int mi = 0; mi < 4; ++mi) {
        acc[mi][ni] = __builtin_amdgcn_mfma_f32_16x16x32_f16(ah[mi], bh, acc[mi][ni], 0, 0, 0);
        acc[mi][ni] = __builtin_amdgcn_mfma_f32_16x16x32_f16(al[mi], bh, acc[mi][ni], 0, 0, 0);
        acc[mi][ni] = __builtin_amdgcn_mfma_f32_16x16x32_f16(ah[mi], bl, acc[mi][ni], 0, 0, 0);
      }
    }
    if (it < 11) __syncthreads();  // all reads done before next stage overwrites
  }

  // epilogue: d = (sq_n + sq_m) - 2g, diag -> FLT_MAX, direct store (line-complete)
  const float* sqb = sq + b * N_;
  float sqm[4];
#pragma unroll
  for (int ni = 0; ni < 4; ++ni) sqm[ni] = sqb[m0 + wc * 64 + ni * 16 + lrow];
  float sqn_[4][4];
#pragma unroll
  for (int mi = 0; mi < 4; ++mi)
#pragma unroll
    for (int r = 0; r < 4; ++r) sqn_[mi][r] = sqb[n0 + wr * 64 + mi * 16 + quad * 4 + r];

  float* Db = D + (size_t)b_local * N_ * N_;
#pragma unroll
  for (int mi = 0; mi < 4; ++mi)
#pragma unroll
    for (int ni = 0; ni < 4; ++ni)
#pragma unroll
      for (int r = 0; r < 4; ++r) {
        const int ng = n0 + wr * 64 + mi * 16 + quad * 4 + r;
        const int mg = m0 + wc * 64 + ni * 16 + lrow;
        float d = fmaf(-2.f, acc[mi][ni][r], sqn_[mi][r] + sqm[ni]);
        if (ng == mg) d = 3.402823466e38f;
        Db[(size_t)ng * N_ + mg] = d;
      }
}

// ---------------- top-9 over D row: 2 rows/wave, 32 lanes/row, f32 value keys ----------
// Selection on VALUES only, then an index-recovery pass. Neighbor ORDER is irrelevant
// downstream (segment-sum): the set = all cols with d < v9 plus lowest-index cols with
// d == v9 to fill to 9 — exactly lax.top_k's stable tie semantics.
__device__ __forceinline__ void ce2f(float& a, float& b) {
  float lo = fminf(a, b), hi = fmaxf(a, b);
  a = lo;
  b = hi;
}

__global__ __launch_bounds__(256) void k_scan(const float* __restrict__ D,
                                              int* __restrict__ nbr, int base_node) {
  const int t = threadIdx.x;
  const int lane = t & 63, wid = t >> 6;
  const int g = lane >> 5;   // row within wave (0..1)
  const int ll = lane & 31;  // lane within 32-lane row group
  const int nl = blockIdx.x * 8 + wid * 2 + g;
  const float* row = D + (size_t)nl * N_ + ll * 32;
  float v[32];
#pragma unroll
  for (int i = 0; i < 8; ++i) {
    float4 q = *(const float4*)(row + i * 4);
    v[i * 4 + 0] = q.x;
    v[i * 4 + 1] = q.y;
    v[i * 4 + 2] = q.z;
    v[i * 4 + 3] = q.w;
  }
  float key[9];
#pragma unroll
  for (int k = 0; k < 9; ++k) key[k] = 3.402823466e38f;
#pragma unroll
  for (int j = 0; j < 32; ++j) {
    key[8] = fminf(key[8], v[j]);
#pragma unroll
    for (int s = 8; s >= 1; --s) ce2f(key[s - 1], key[s]);
  }
#pragma unroll
  for (int lvl = 1; lvl < 32; lvl <<= 1) {
    float pk[9];
#pragma unroll
    for (int k = 0; k < 9; ++k) pk[k] = __shfl_xor(key[k], lvl, 64);
    float m[9];
#pragma unroll
    for (int k = 0; k < 9; ++k) m[k] = fminf(key[k], pk[8 - k]);
    ce2f(m[0], m[8]);
    ce2f(m[1], m[5]); ce2f(m[2], m[6]); ce2f(m[3], m[7]); ce2f(m[4], m[8]);
    ce2f(m[1], m[3]); ce2f(m[2], m[4]); ce2f(m[5], m[7]); ce2f(m[6], m[8]);
    ce2f(m[1], m[2]); ce2f(m[3], m[4]); ce2f(m[5], m[6]); ce2f(m[7], m[8]);
#pragma unroll
    for (int k = 0; k < 9; ++k) key[k] = m[k];
  }
  const float v9 = key[8];
  int c_lt = 0;
#pragma unroll
  for (int k = 0; k < 8; ++k) c_lt += (key[k] < v9) ? 1 : 0;

  unsigned lt_mask = 0u, eq_mask = 0u;
#pragma unroll
  for (int j = 0; j < 32; ++j) {
    lt_mask |= (v[j] < v9) ? (1u << j) : 0u;
    eq_mask |= (v[j] == v9) ? (1u << j) : 0u;
  }
  const int lt_cnt = __popc(lt_mask), eq_cnt = __popc(eq_mask);
  int packed = lt_cnt | (eq_cnt << 16);
  int run = packed;
#pragma unroll
  for (int off = 1; off < 32; off <<= 1) {
    int q = __shfl_up(run, off, 32);
    if (ll >= off) run += q;
  }
  const int pref = run - packed;
  const int lt_pref = pref & 0xFFFF, eq_pref = pref >> 16;

  int* np = nbr + (size_t)(base_node + nl) * K_;
  int slot = lt_pref;
  unsigned m = lt_mask;
  while (m) {
    int j = __builtin_ctz(m);
    m &= m - 1;
    np[slot++] = ll * 32 + j;
  }
  slot = c_lt + eq_pref;
  m = eq_mask;
  while (m && slot < 9) {
    int j = __builtin_ctz(m);
    m &= m - 1;
    np[slot++] = ll * 32 + j;
  }
}

// ---------------- MFMA xw[b][co][n]: A=Wg(h/l), B=xT(h/l), dbuf staging ----------------
// XCD swizzle: the 6 ct-blocks sharing one (b,nt) B-tile get bids congruent mod 8 ->
// same XCD -> B-tile fetched once into that XCD's L2.
__global__ __launch_bounds__(256, 3) void k_xw(const ushort* __restrict__ xhT,
                                               const ushort* __restrict__ xlT,
                                               const ushort* __restrict__ WgH,
                                               const ushort* __restrict__ WgL,
                                               float* __restrict__ xw) {
  const int bid = blockIdx.x;
  const int xcd = bid & 7, j = bid >> 3;   // 96 blocks per XCD
  const int pair = xcd * 16 + j / 6;       // (b,nt) pair; 6 consecutive j share it
  const int ct = j % 6;
  const int b = pair >> 3, nt = pair & 7;
  const int co0 = ct * 64, n0 = nt * 128;
  __shared__ alignas(16) char sm[2][24576];  // per buf: Ah@0 Al@4096 Bh@8192 Bl@16384
  const int t = threadIdx.x;
  const int lane = t & 63, wid = t >> 6, quad = lane >> 4, lrow = lane & 15;
  const int wr = wid >> 1, wc = wid & 1;
  const int lrow4 = lane >> 2, lpos = lane & 3;

  f32x4 acc[2][4];
#pragma unroll
  for (int mi = 0; mi < 2; ++mi)
#pragma unroll
    for (int ni = 0; ni < 4; ++ni) acc[mi][ni] = (f32x4){0.f, 0.f, 0.f, 0.f};

  const char* asrc[2] = {(const char*)(WgH + (size_t)co0 * C_),
                         (const char*)(WgL + (size_t)co0 * C_)};
  const char* bsrc[2] = {(const char*)(xhT + (size_t)(b * N_ + n0) * C_),
                         (const char*)(xlT + (size_t)(b * N_ + n0) * C_)};

  auto stage = [&](int it) {
    char* dst = sm[it & 1];
    const int ktB = it * 64;
#pragma unroll
    for (int i = 0; i < 6; ++i) {
      const int c = wid * 6 + i;
      const char* src;
      int base, row;
      if (c < 8) {
        const int arr = c >> 2, sub = c & 3;
        src = asrc[arr];
        base = arr * 4096 + sub * 1024;
        row = sub * 16 + lrow4;
      } else {
        const int cc = c - 8, arr = cc >> 3, sub = cc & 7;
        src = bsrc[arr];
        base = 8192 + arr * 8192 + sub * 1024;
        row = sub * 16 + lrow4;
      }
      const int swz = lpos ^ ((row >> 1) & 3);
      gld_lds16(src + (size_t)row * 768 + ktB + swz * 16, dst + base + lane * 16);
    }
  };

  stage(0);
  for (int it = 0; it < 12; ++it) {
    __syncthreads();
    if (it < 11) stage(it + 1);
    const char* smb = sm[it & 1];
    f16x8 bh[4], bl[4];
#pragma unroll
    for (int ni = 0; ni < 4; ++ni) {
      const int row = wr * 64 + ni * 16 + lrow;
      const int off = row * 64 + (quad ^ ((row >> 1) & 3)) * 16;
      bh[ni] = *(const f16x8*)(smb + 8192 + off);
      bl[ni] = *(const f16x8*)(smb + 16384 + off);
    }
#pragma unroll
    for (int mi = 0; mi < 2; ++mi) {
      const int row = wc * 32 + mi * 16 + lrow;
      const int off = row * 64 + (quad ^ ((row >> 1) & 3)) * 16;
      f16x8 ah = *(const f16x8*)(smb + off);
      f16x8 al = *(const f16x8*)(smb + 4096 + off);
#pragma unroll
      for (int ni = 0; ni < 4; ++ni) {
        acc[mi][ni] = __builtin_amdgcn_mfma_f32_16x16x32_f16(ah, bh[ni], acc[mi][ni], 0, 0, 0);
        acc[mi][ni] = __builtin_amdgcn_mfma_f32_16x16x32_f16(al, bh[ni], acc[mi][ni], 0, 0, 0);
        acc[mi][ni] = __builtin_amdgcn_mfma_f32_16x16x32_f16(ah, bl[ni], acc[mi][ni], 0, 0, 0);
      }
    }
  }
#pragma unroll
  for (int mi = 0; mi < 2; ++mi)
#pragma unroll
    for (int ni = 0; ni < 4; ++ni)
#pragma unroll
      for (int r = 0; r < 4; ++r) {
        const int c_g = co0 + wc * 32 + mi * 16 + quad * 4 + r;
        const int n_g = n0 + wr * 64 + ni * 16 + lrow;
        xw[((size_t)b * C_ + c_g) * N_ + n_g] = acc[mi][ni][r];
      }
}

// ---------------- aggregate (deg==10 uniformly) + BN partial stats ----------------
// 8 channels per block: nbr staged once per 8 channels, the 9 neighbor indices read
// once and reused 8x.
__global__ __launch_bounds__(256) void k_agg(const float* __restrict__ xw,
                                             const int* __restrict__ nbr,
                                             const float* __restrict__ bg,
                                             float* __restrict__ out,
                                             float* __restrict__ stats) {
  const int ct = blockIdx.x % (C_ / 8);  // 48
  const int b = blockIdx.x / (C_ / 8);
  const int c0 = ct * 8;
  __shared__ alignas(16) int nb_l[N_ * K_];       // 36864 B
  __shared__ alignas(16) float row_l[8][N_ + 4];  // 32896 B
  __shared__ float red[2][8][4];
  const int tid = threadIdx.x;
  const int4* gp = (const int4*)(nbr + (size_t)b * N_ * K_);
  int4* lp = (int4*)nb_l;
  for (int t = tid; t < N_ * K_ / 4; t += 256) lp[t] = gp[t];
  for (int t = tid; t < 8 * (N_ / 4); t += 256) {
    const int j = t >> 8, n4 = t & 255;  // N_/4 = 256
    float4 v = ((const float4*)(xw + ((size_t)(b * C_ + c0 + j)) * N_))[n4];
    *(float4*)&row_l[j][n4 * 4] = v;
  }
  __syncthreads();
  float bgc[8];
#pragma unroll
  for (int j = 0; j < 8; ++j) bgc[j] = bg[c0 + j];
  float s1[8], s2[8];
#pragma unroll
  for (int j = 0; j < 8; ++j) {
    s1[j] = 0.f;
    s2[j] = 0.f;
  }
  float* outb = out + ((size_t)b * C_ + c0) * N_;
#pragma unroll
  for (int s = 0; s < 4; ++s) {
    const int n = tid + 256 * s;
    const int* nn_ = &nb_l[n * K_];
    int idx[K_];
#pragma unroll
    for (int k = 0; k < K_; ++k) idx[k] = nn_[k];
    float a[8];
#pragma unroll
    for (int j = 0; j < 8; ++j) a[j] = row_l[j][n];
#pragma unroll
    for (int k = 0; k < K_; ++k) {
      const int m = idx[k];
#pragma unroll
      for (int j = 0; j < 8; ++j) a[j] += row_l[j][m];
    }
#pragma unroll
    for (int j = 0; j < 8; ++j) {
      float y = fmaf(a[j], 0.099999994f, bgc[j]);
      outb[(size_t)j * N_ + n] = y;
      s1[j] += y;
      s2[j] = fmaf(y, y, s2[j]);
    }
  }
#pragma unroll
  for (int off = 32; off > 0; off >>= 1)
#pragma unroll
    for (int j = 0; j < 8; ++j) {
      s1[j] += __shfl_down(s1[j], off, 64);
      s2[j] += __shfl_down(s2[j], off, 64);
    }
  const int lane = tid & 63, wid = tid >> 6;
  if (lane == 0)
#pragma unroll
    for (int j = 0; j < 8; ++j) {
      red[0][j][wid] = s1[j];
      red[1][j][wid] = s2[j];
    }
  __syncthreads();
  if (tid < 16) {
    const int j = tid & 7, which = tid >> 3;
    float v = red[which][j][0] + red[which][j][1] + red[which][j][2] + red[which][j][3];
    atomicAdd(&stats[which * C_ + c0 + j], v);
  }
}

// ---------------- BN (batch stats) + tanh-GELU + residual ----------------
__global__ void k_bn(const float* __restrict__ x, const float* __restrict__ gamma,
                     const float* __restrict__ beta, const float* __restrict__ stats,
                     float* __restrict__ out) {
  const int f = blockIdx.x * blockDim.x + threadIdx.x;
  const int e = f * 4;
  const int c = (e >> 10) % C_;
  const float inv = 1.f / 16384.f;
  const float mu = stats[c] * inv;
  const float var = fmaf(-mu, mu, stats[C_ + c] * inv);
  const float sc = gamma[c] * rsqrtf(var + 1e-5f);
  const float sh = fmaf(-mu, sc, beta[c]);
  float4 y = ((const float4*)out)[f];
  float4 xv = ((const float4*)x)[f];
  auto gl = [](float z) {
    float z3 = z * z * z;
    float t = 0.7978845608028654f * fmaf(0.044715f, z3, z);
    float th = tanhf(t);
    return 0.5f * z * (1.f + th);
  };
  float4 o;
  o.x = gl(fmaf(y.x, sc, sh)) + xv.x;
  o.y = gl(fmaf(y.y, sc, sh)) + xv.y;
  o.z = gl(fmaf(y.z, sc, sh)) + xv.z;
  o.w = gl(fmaf(y.w, sc, sh)) + xv.w;
  ((float4*)out)[f] = o;
}

extern "C" void kernel_launch(void* const* d_in, const int* in_sizes, int n_in,
                              void* d_out, int out_size, void* d_ws, size_t ws_size,
                              hipStream_t stream) {
  const float* x = (const float*)d_in[0];
  const float* Wg = (const float*)d_in[1];
  const float* bg = (const float*)d_in[2];
  const float* gamma = (const float*)d_in[3];
  const float* beta = (const float*)d_in[4];
  float* out = (float*)d_out;

  int nb;
  if (ws_size >= 94000000) nb = 16;
  else if (ws_size >= 60500000) nb = 8;
  else nb = 4;

  char* ws = (char*)d_ws;
  ushort* xhT = (ushort*)ws;                  // @0          12,582,912
  ushort* xlT = (ushort*)(ws + 12582912);     //             12,582,912
  ushort* WgH = (ushort*)(ws + 25165824);     //                294,912
  ushort* WgL = (ushort*)(ws + 25460736);     //                294,912
  float* sq = (float*)(ws + 25755648);        //                 65,536
  float* Dbuf = (float*)(ws + 25821184);      // nb*4,194,304
  float* xw = (float*)(ws + 25821184);        // overlays Dbuf (Dbuf dead after scans)
  double* sqpart = (double*)(ws + 25821184);  // overlays Dbuf head (2MB, dead before gram)
  size_t dreg = (size_t)nb * 4194304;
  if (dreg < 25165824) dreg = 25165824;       // xw needs 25.17 MB
  int* nbr = (int*)(ws + 25821184 + dreg);    //                589,824
  float* stats = (float*)(ws + 25821184 + dreg + 589824);  //     3,072

  hipMemsetAsync(stats, 0, 2 * C_ * sizeof(float), stream);
  k_cvt<<<3072, 256, 0, stream>>>(x, xhT, xlT);
  k_cvtw<<<144, 256, 0, stream>>>(Wg, WgH, WgL);
  k_sq1<<<1024, 256, 0, stream>>>(x, sqpart);
  k_sq2<<<64, 256, 0, stream>>>(sqpart, sq);
  for (int r = 0; r < B_ / nb; ++r) {
    k_gram<<<nb * 64, 256, 0, stream>>>(xhT, xlT, sq, Dbuf, r * nb, nb);
    k_scan<<<nb * 128, 256, 0, stream>>>(Dbuf, nbr, r * nb * N_);
  }
  k_xw<<<768, 256, 0, stream>>>(xhT, xlT, WgH, WgL, xw);
  k_agg<<<B_ * (C_ / 8), 256, 0, stream>>>(xw, nbr, bg, out, stats);
  k_bn<<<6144, 256, 0, stream>>>(x, gamma, beta, stats, out);
}

// Round 5
// 219.481 us; speedup vs baseline: 1.1620x; 1.0731x over previous
//
#include <hip/hip_runtime.h>
#include <math.h>

#define B_ 16
#define C_ 384
#define N_ 1024
#define K_ 9

typedef _Float16 f16x8 __attribute__((ext_vector_type(8)));
typedef _Float16 f16x4 __attribute__((ext_vector_type(4)));
typedef float f32x4 __attribute__((ext_vector_type(4)));
typedef unsigned long long u64;

__device__ __forceinline__ void gld_lds16(const void* g, void* l) {
  __builtin_amdgcn_global_load_lds((const __attribute__((address_space(1))) void*)g,
                                   (__attribute__((address_space(3))) void*)l, 16, 0, 0);
}

// ---------------- transpose + fp16 split: x[b][c][n] -> xhT/xlT [b][n][c] ----------------
__global__ void k_cvt(const float* __restrict__ x, ushort* __restrict__ xhT,
                      ushort* __restrict__ xlT) {
  const int bid = blockIdx.x;  // ((b*16 + nt)*12 + ct)
  const int ct = bid % 12;
  const int nt = (bid / 12) & 15;
  const int b = bid / 192;
  const int c0 = ct * 32, n0 = nt * 64;
  __shared__ float ld[32 * 65];
  const int t = threadIdx.x;
  {
    const int c = t >> 3, n8 = (t & 7) * 8;
    const float* src = x + ((size_t)(b * C_ + c0 + c) * N_ + n0 + n8);
    float4 v0 = *(const float4*)src;
    float4 v1 = *(const float4*)(src + 4);
    float vv[8] = {v0.x, v0.y, v0.z, v0.w, v1.x, v1.y, v1.z, v1.w};
#pragma unroll
    for (int j = 0; j < 8; ++j) ld[c * 65 + n8 + j] = vv[j];
  }
  __syncthreads();
  {
    const int n = t >> 2, c8 = (t & 3) * 8;
    f16x8 hv, lv;
#pragma unroll
    for (int j = 0; j < 8; ++j) {
      float v = ld[(c8 + j) * 65 + n];
      _Float16 h = (_Float16)v;
      _Float16 l = (_Float16)(v - (float)h);
      hv[j] = h;
      lv[j] = l;
    }
    const size_t off = (size_t)(b * N_ + n0 + n) * C_ + c0 + c8;
    *(f16x8*)(xhT + off) = hv;
    *(f16x8*)(xlT + off) = lv;
  }
}

// ---------------- Wg -> WgH/WgL ----------------
__global__ void k_cvtw(const float* __restrict__ Wg, ushort* __restrict__ WgH,
                       ushort* __restrict__ WgL) {
  const int i = (blockIdx.x * 256 + threadIdx.x) * 4;  // 144 blocks
  float4 v = *(const float4*)(Wg + i);
  float vv[4] = {v.x, v.y, v.z, v.w};
  f16x4 hv, lv;
#pragma unroll
  for (int j = 0; j < 4; ++j) {
    _Float16 h = (_Float16)vv[j];
    hv[j] = h;
    lv[j] = (_Float16)(vv[j] - (float)h);
  }
  *(f16x4*)(WgH + i) = hv;
  *(f16x4*)(WgL + i) = lv;
}

// ---------------- sq pass 1: partial sums over 24-channel chunks (fp64) ----------------
__global__ void k_sq1(const float* __restrict__ x, double* __restrict__ part) {
  const int bid = blockIdx.x;
  const int b = bid >> 6, q = (bid >> 2) & 15, nt = bid & 3;
  const int n = nt * 256 + threadIdx.x;
  const float* xb = x + ((size_t)b * C_ + q * 24) * N_ + n;
  double s = 0.0;
#pragma unroll 4
  for (int c = 0; c < 24; ++c) {
    float v = xb[(size_t)c * N_];
    s = fma((double)v, (double)v, s);
  }
  part[((size_t)b * 16 + q) * N_ + n] = s;
}

// ---------------- sq pass 2: deterministic reduce of 16 partials ----------------
__global__ void k_sq2(const double* __restrict__ part, float* __restrict__ sq) {
  const int idx = blockIdx.x * blockDim.x + threadIdx.x;
  const int b = idx >> 10, n = idx & 1023;
  const double* p = part + (size_t)b * 16 * N_ + n;
  double s = 0.0;
#pragma unroll
  for (int q = 0; q < 16; ++q) s += p[(size_t)q * N_];
  sq[idx] = (float)s;
}

// ---------------- MFMA Gram -> D[b_local][n][m] (pure GEMM, dbuf staging) ----------------
// R2-proven structure (43us, WRITE=65.5MB, MfmaUtil 36%): grid nb*64, XCD swizzle
// (nb>=8): batch group = bid&7 -> L2-resident working set. LDS 2x32KB: per buf Ah@0
// Al@8192 Bh@16384 Bl@24576, packed 64B rows, XOR-chunk swizzle. Prefetch distance 1:
// stage(it+1) issued before compute(it) -> the barrier drain waits on loads that are a
// full compute-phase old.
__global__ __launch_bounds__(256, 2) void k_gram(const ushort* __restrict__ xhT,
                                                 const ushort* __restrict__ xlT,
                                                 const float* __restrict__ sq,
                                                 float* __restrict__ D, int base_b, int nb) {
  const int bid = blockIdx.x;
  int b_local, pid;
  if (nb >= 8) {
    const int x = bid & 7, j = bid >> 3, grp = nb >> 3;
    b_local = x * grp + (j >> 6);
    pid = j & 63;
  } else {
    b_local = bid >> 6;
    pid = bid & 63;
  }
  const int b = base_b + b_local;
  const int rt = pid >> 3, mt = pid & 7;
  const int n0 = rt * 128, m0 = mt * 128;

  __shared__ alignas(16) char sm[2][32768];
  const int t = threadIdx.x;
  const int lane = t & 63, wid = t >> 6, quad = lane >> 4, lrow = lane & 15;
  const int wr = wid >> 1, wc = wid & 1;
  const int lrow4 = lane >> 2, lpos = lane & 3;

  // wave -> array it stages: 0:Ah(n0,h) 1:Al(n0,l) 2:Bh(m0,h) 3:Bl(m0,l)
  const char* src = (const char*)((wid & 1) ? xlT : xhT) +
                    (size_t)(b * N_ + ((wid >> 1) ? m0 : n0)) * C_ * 2;

  f32x4 acc[4][4];
#pragma unroll
  for (int mi = 0; mi < 4; ++mi)
#pragma unroll
    for (int ni = 0; ni < 4; ++ni) acc[mi][ni] = (f32x4){0.f, 0.f, 0.f, 0.f};

  auto stage = [&](int it) {
    char* dst = sm[it & 1] + wid * 8192;
    const int ktB = it * 64;
#pragma unroll
    for (int i = 0; i < 8; ++i) {
      const int row = i * 16 + lrow4;
      const int swz = lpos ^ ((row >> 1) & 3);
      gld_lds16(src + (size_t)row * 768 + ktB + swz * 16, dst + i * 1024 + lane * 16);
    }
  };

  stage(0);
  for (int it = 0; it < 12; ++it) {
    __syncthreads();
    if (it < 11) stage(it + 1);
    const char* smb = sm[it & 1];
    f16x8 ah[4], al[4];
#pragma unroll
    for (int mi = 0; mi < 4; ++mi) {
      const int row = wr * 64 + mi * 16 + lrow;
      const int off = row * 64 + (quad ^ ((row >> 1) & 3)) * 16;
      ah[mi] = *(const f16x8*)(smb + off);
      al[mi] = *(const f16x8*)(smb + 8192 + off);
    }
#pragma unroll
    for (int ni = 0; ni < 4; ++ni) {
      const int row = wc * 64 + ni * 16 + lrow;
      const int off = row * 64 + (quad ^ ((row >> 1) & 3)) * 16;
      f16x8 bh = *(const f16x8*)(smb + 16384 + off);
      f16x8 bl = *(const f16x8*)(smb + 24576 + off);
#pragma unroll
      for (int mi = 0; mi < 4; ++mi) {
        acc[mi][ni] = __builtin_amdgcn_mfma_f32_16x16x32_f16(ah[mi], bh, acc[mi][ni], 0, 0, 0);
        acc[mi][ni] = __builtin_amdgcn_mfma_f32_16x16x32_f16(al[mi], bh, acc[mi][ni], 0, 0, 0);
        acc[mi][ni] = __builtin_amdgcn_mfma_f32_16x16x32_f16(ah[mi], bl, acc[mi][ni], 0, 0, 0);
      }
    }
  }

  // epilogue: d = (sq_n + sq_m) - 2g, diag -> FLT_MAX, direct store (L2 write-combines)
  const float* sqb = sq + b * N_;
  float sqm[4];
#pragma unroll
  for (int ni = 0; ni < 4; ++ni) sqm[ni] = sqb[m0 + wc * 64 + ni * 16 + lrow];
  float sqn_[4][4];
#pragma unroll
  for (int mi = 0; mi < 4; ++mi)
#pragma unroll
    for (int r = 0; r < 4; ++r) sqn_[mi][r] = sqb[n0 + wr * 64 + mi * 16 + quad * 4 + r];

  float* Db = D + (size_t)b_local * N_ * N_;
#pragma unroll
  for (int mi = 0; mi < 4; ++mi)
#pragma unroll
    for (int ni = 0; ni < 4; ++ni)
#pragma unroll
      for (int r = 0; r < 4; ++r) {
        const int ng = n0 + wr * 64 + mi * 16 + quad * 4 + r;
        const int mg = m0 + wc * 64 + ni * 16 + lrow;
        float d = fmaf(-2.f, acc[mi][ni][r], sqn_[mi][r] + sqm[ni]);
        if (ng == mg) d = 3.402823466e38f;
        Db[(size_t)ng * N_ + mg] = d;
      }
}

// ---------------- top-9 over D row: 2 rows/wave, 32 lanes/row, f32 value keys ----------
// Selection on VALUES only, then an index-recovery pass. Neighbor ORDER is irrelevant
// downstream (segment-sum): the set = all cols with d < v9 plus lowest-index cols with
// d == v9 to fill to 9 — exactly lax.top_k's stable tie semantics.
__device__ __forceinline__ void ce2f(float& a, float& b) {
  float lo = fminf(a, b), hi = fmaxf(a, b);
  a = lo;
  b = hi;
}

__global__ __launch_bounds__(256) void k_scan(const float* __restrict__ D,
                                              int* __restrict__ nbr, int base_node) {
  const int t = threadIdx.x;
  const int lane = t & 63, wid = t >> 6;
  const int g = lane >> 5;   // row within wave (0..1)
  const int ll = lane & 31;  // lane within 32-lane row group
  const int nl = blockIdx.x * 8 + wid * 2 + g;
  const float* row = D + (size_t)nl * N_ + ll * 32;
  float v[32];
#pragma unroll
  for (int i = 0; i < 8; ++i) {
    float4 q = *(const float4*)(row + i * 4);
    v[i * 4 + 0] = q.x;
    v[i * 4 + 1] = q.y;
    v[i * 4 + 2] = q.z;
    v[i * 4 + 3] = q.w;
  }
  float key[9];
#pragma unroll
  for (int k = 0; k < 9; ++k) key[k] = 3.402823466e38f;
#pragma unroll
  for (int j = 0; j < 32; ++j) {
    key[8] = fminf(key[8], v[j]);
#pragma unroll
    for (int s = 8; s >= 1; --s) ce2f(key[s - 1], key[s]);
  }
#pragma unroll
  for (int lvl = 1; lvl < 32; lvl <<= 1) {
    float pk[9];
#pragma unroll
    for (int k = 0; k < 9; ++k) pk[k] = __shfl_xor(key[k], lvl, 64);
    float m[9];
#pragma unroll
    for (int k = 0; k < 9; ++k) m[k] = fminf(key[k], pk[8 - k]);
    ce2f(m[0], m[8]);
    ce2f(m[1], m[5]); ce2f(m[2], m[6]); ce2f(m[3], m[7]); ce2f(m[4], m[8]);
    ce2f(m[1], m[3]); ce2f(m[2], m[4]); ce2f(m[5], m[7]); ce2f(m[6], m[8]);
    ce2f(m[1], m[2]); ce2f(m[3], m[4]); ce2f(m[5], m[6]); ce2f(m[7], m[8]);
#pragma unroll
    for (int k = 0; k < 9; ++k) key[k] = m[k];
  }
  const float v9 = key[8];
  int c_lt = 0;
#pragma unroll
  for (int k = 0; k < 8; ++k) c_lt += (key[k] < v9) ? 1 : 0;

  unsigned lt_mask = 0u, eq_mask = 0u;
#pragma unroll
  for (int j = 0; j < 32; ++j) {
    lt_mask |= (v[j] < v9) ? (1u << j) : 0u;
    eq_mask |= (v[j] == v9) ? (1u << j) : 0u;
  }
  const int lt_cnt = __popc(lt_mask), eq_cnt = __popc(eq_mask);
  int packed = lt_cnt | (eq_cnt << 16);
  int run = packed;
#pragma unroll
  for (int off = 1; off < 32; off <<= 1) {
    int q = __shfl_up(run, off, 32);
    if (ll >= off) run += q;
  }
  const int pref = run - packed;
  const int lt_pref = pref & 0xFFFF, eq_pref = pref >> 16;

  int* np = nbr + (size_t)(base_node + nl) * K_;
  int slot = lt_pref;
  unsigned m = lt_mask;
  while (m) {
    int j = __builtin_ctz(m);
    m &= m - 1;
    np[slot++] = ll * 32 + j;
  }
  slot = c_lt + eq_pref;
  m = eq_mask;
  while (m && slot < 9) {
    int j = __builtin_ctz(m);
    m &= m - 1;
    np[slot++] = ll * 32 + j;
  }
}

// ---------------- MFMA xw[b][co][n]: A=Wg(h/l), B=xT(h/l), dbuf staging ----------------
// XCD swizzle: the 6 ct-blocks sharing one (b,nt) B-tile get bids congruent mod 8 ->
// same XCD -> B-tile fetched once into that XCD's L2.
__global__ __launch_bounds__(256, 3) void k_xw(const ushort* __restrict__ xhT,
                                               const ushort* __restrict__ xlT,
                                               const ushort* __restrict__ WgH,
                                               const ushort* __restrict__ WgL,
                                               float* __restrict__ xw) {
  const int bid = blockIdx.x;
  const int xcd = bid & 7, j = bid >> 3;   // 96 blocks per XCD
  const int pair = xcd * 16 + j / 6;       // (b,nt) pair; 6 consecutive j share it
  const int ct = j % 6;
  const int b = pair >> 3, nt = pair & 7;
  const int co0 = ct * 64, n0 = nt * 128;
  __shared__ alignas(16) char sm[2][24576];  // per buf: Ah@0 Al@4096 Bh@8192 Bl@16384
  const int t = threadIdx.x;
  const int lane = t & 63, wid = t >> 6, quad = lane >> 4, lrow = lane & 15;
  const int wr = wid >> 1, wc = wid & 1;
  const int lrow4 = lane >> 2, lpos = lane & 3;

  f32x4 acc[2][4];
#pragma unroll
  for (int mi = 0; mi < 2; ++mi)
#pragma unroll
    for (int ni = 0; ni < 4; ++ni) acc[mi][ni] = (f32x4){0.f, 0.f, 0.f, 0.f};

  const char* asrc[2] = {(const char*)(WgH + (size_t)co0 * C_),
                         (const char*)(WgL + (size_t)co0 * C_)};
  const char* bsrc[2] = {(const char*)(xhT + (size_t)(b * N_ + n0) * C_),
                         (const char*)(xlT + (size_t)(b * N_ + n0) * C_)};

  auto stage = [&](int it) {
    char* dst = sm[it & 1];
    const int ktB = it * 64;
#pragma unroll
    for (int i = 0; i < 6; ++i) {
      const int c = wid * 6 + i;
      const char* src;
      int base, row;
      if (c < 8) {
        const int arr = c >> 2, sub = c & 3;
        src = asrc[arr];
        base = arr * 4096 + sub * 1024;
        row = sub * 16 + lrow4;
      } else {
        const int cc = c - 8, arr = cc >> 3, sub = cc & 7;
        src = bsrc[arr];
        base = 8192 + arr * 8192 + sub * 1024;
        row = sub * 16 + lrow4;
      }
      const int swz = lpos ^ ((row >> 1) & 3);
      gld_lds16(src + (size_t)row * 768 + ktB + swz * 16, dst + base + lane * 16);
    }
  };

  stage(0);
  for (int it = 0; it < 12; ++it) {
    __syncthreads();
    if (it < 11) stage(it + 1);
    const char* smb = sm[it & 1];
    f16x8 bh[4], bl[4];
#pragma unroll
    for (int ni = 0; ni < 4; ++ni) {
      const int row = wr * 64 + ni * 16 + lrow;
      const int off = row * 64 + (quad ^ ((row >> 1) & 3)) * 16;
      bh[ni] = *(const f16x8*)(smb + 8192 + off);
      bl[ni] = *(const f16x8*)(smb + 16384 + off);
    }
#pragma unroll
    for (int mi = 0; mi < 2; ++mi) {
      const int row = wc * 32 + mi * 16 + lrow;
      const int off = row * 64 + (quad ^ ((row >> 1) & 3)) * 16;
      f16x8 ah = *(const f16x8*)(smb + off);
      f16x8 al = *(const f16x8*)(smb + 4096 + off);
#pragma unroll
      for (int ni = 0; ni < 4; ++ni) {
        acc[mi][ni] = __builtin_amdgcn_mfma_f32_16x16x32_f16(ah, bh[ni], acc[mi][ni], 0, 0, 0);
        acc[mi][ni] = __builtin_amdgcn_mfma_f32_16x16x32_f16(al, bh[ni], acc[mi][ni], 0, 0, 0);
        acc[mi][ni] = __builtin_amdgcn_mfma_f32_16x16x32_f16(ah, bl[ni], acc[mi][ni], 0, 0, 0);
      }
    }
  }
#pragma unroll
  for (int mi = 0; mi < 2; ++mi)
#pragma unroll
    for (int ni = 0; ni < 4; ++ni)
#pragma unroll
      for (int r = 0; r < 4; ++r) {
        const int c_g = co0 + wc * 32 + mi * 16 + quad * 4 + r;
        const int n_g = n0 + wr * 64 + ni * 16 + lrow;
        xw[((size_t)b * C_ + c_g) * N_ + n_g] = acc[mi][ni][r];
      }
}

// ---------------- aggregate (deg==10 uniformly) + BN partial stats ----------------
// 8 channels per block: nbr staged once per 8 channels, the 9 neighbor indices read
// once and reused 8x.
__global__ __launch_bounds__(256) void k_agg(const float* __restrict__ xw,
                                             const int* __restrict__ nbr,
                                             const float* __restrict__ bg,
                                             float* __restrict__ out,
                                             float* __restrict__ stats) {
  const int ct = blockIdx.x % (C_ / 8);  // 48
  const int b = blockIdx.x / (C_ / 8);
  const int c0 = ct * 8;
  __shared__ alignas(16) int nb_l[N_ * K_];       // 36864 B
  __shared__ alignas(16) float row_l[8][N_ + 4];  // 32896 B
  __shared__ float red[2][8][4];
  const int tid = threadIdx.x;
  const int4* gp = (const int4*)(nbr + (size_t)b * N_ * K_);
  int4* lp = (int4*)nb_l;
  for (int t = tid; t < N_ * K_ / 4; t += 256) lp[t] = gp[t];
  for (int t = tid; t < 8 * (N_ / 4); t += 256) {
    const int j = t >> 8, n4 = t & 255;  // N_/4 = 256
    float4 v = ((const float4*)(xw + ((size_t)(b * C_ + c0 + j)) * N_))[n4];
    *(float4*)&row_l[j][n4 * 4] = v;
  }
  __syncthreads();
  float bgc[8];
#pragma unroll
  for (int j = 0; j < 8; ++j) bgc[j] = bg[c0 + j];
  float s1[8], s2[8];
#pragma unroll
  for (int j = 0; j < 8; ++j) {
    s1[j] = 0.f;
    s2[j] = 0.f;
  }
  float* outb = out + ((size_t)b * C_ + c0) * N_;
#pragma unroll
  for (int s = 0; s < 4; ++s) {
    const int n = tid + 256 * s;
    const int* nn_ = &nb_l[n * K_];
    int idx[K_];
#pragma unroll
    for (int k = 0; k < K_; ++k) idx[k] = nn_[k];
    float a[8];
#pragma unroll
    for (int j = 0; j < 8; ++j) a[j] = row_l[j][n];
#pragma unroll
    for (int k = 0; k < K_; ++k) {
      const int m = idx[k];
#pragma unroll
      for (int j = 0; j < 8; ++j) a[j] += row_l[j][m];
    }
#pragma unroll
    for (int j = 0; j < 8; ++j) {
      float y = fmaf(a[j], 0.099999994f, bgc[j]);
      outb[(size_t)j * N_ + n] = y;
      s1[j] += y;
      s2[j] = fmaf(y, y, s2[j]);
    }
  }
#pragma unroll
  for (int off = 32; off > 0; off >>= 1)
#pragma unroll
    for (int j = 0; j < 8; ++j) {
      s1[j] += __shfl_down(s1[j], off, 64);
      s2[j] += __shfl_down(s2[j], off, 64);
    }
  const int lane = tid & 63, wid = tid >> 6;
  if (lane == 0)
#pragma unroll
    for (int j = 0; j < 8; ++j) {
      red[0][j][wid] = s1[j];
      red[1][j][wid] = s2[j];
    }
  __syncthreads();
  if (tid < 16) {
    const int j = tid & 7, which = tid >> 3;
    float v = red[which][j][0] + red[which][j][1] + red[which][j][2] + red[which][j][3];
    atomicAdd(&stats[which * C_ + c0 + j], v);
  }
}

// ---------------- BN (batch stats) + tanh-GELU + residual ----------------
__global__ void k_bn(const float* __restrict__ x, const float* __restrict__ gamma,
                     const float* __restrict__ beta, const float* __restrict__ stats,
                     float* __restrict__ out) {
  const int f = blockIdx.x * blockDim.x + threadIdx.x;
  const int e = f * 4;
  const int c = (e >> 10) % C_;
  const float inv = 1.f / 16384.f;
  const float mu = stats[c] * inv;
  const float var = fmaf(-mu, mu, stats[C_ + c] * inv);
  const float sc = gamma[c] * rsqrtf(var + 1e-5f);
  const float sh = fmaf(-mu, sc, beta[c]);
  float4 y = ((const float4*)out)[f];
  float4 xv = ((const float4*)x)[f];
  auto gl = [](float z) {
    float z3 = z * z * z;
    float t = 0.7978845608028654f * fmaf(0.044715f, z3, z);
    float th = tanhf(t);
    return 0.5f * z * (1.f + th);
  };
  float4 o;
  o.x = gl(fmaf(y.x, sc, sh)) + xv.x;
  o.y = gl(fmaf(y.y, sc, sh)) + xv.y;
  o.z = gl(fmaf(y.z, sc, sh)) + xv.z;
  o.w = gl(fmaf(y.w, sc, sh)) + xv.w;
  ((float4*)out)[f] = o;
}

extern "C" void kernel_launch(void* const* d_in, const int* in_sizes, int n_in,
                              void* d_out, int out_size, void* d_ws, size_t ws_size,
                              hipStream_t stream) {
  const float* x = (const float*)d_in[0];
  const float* Wg = (const float*)d_in[1];
  const float* bg = (const float*)d_in[2];
  const float* gamma = (const float*)d_in[3];
  const float* beta = (const float*)d_in[4];
  float* out = (float*)d_out;

  int nb;
  if (ws_size >= 94000000) nb = 16;
  else if (ws_size >= 60500000) nb = 8;
  else nb = 4;

  char* ws = (char*)d_ws;
  ushort* xhT = (ushort*)ws;                  // @0          12,582,912
  ushort* xlT = (ushort*)(ws + 12582912);     //             12,582,912
  ushort* WgH = (ushort*)(ws + 25165824);     //                294,912
  ushort* WgL = (ushort*)(ws + 25460736);     //                294,912
  float* sq = (float*)(ws + 25755648);        //                 65,536
  float* Dbuf = (float*)(ws + 25821184);      // nb*4,194,304
  float* xw = (float*)(ws + 25821184);        // overlays Dbuf (Dbuf dead after scans)
  double* sqpart = (double*)(ws + 25821184);  // overlays Dbuf head (2MB, dead before gram)
  size_t dreg = (size_t)nb * 4194304;
  if (dreg < 25165824) dreg = 25165824;       // xw needs 25.17 MB
  int* nbr = (int*)(ws + 25821184 + dreg);    //                589,824
  float* stats = (float*)(ws + 25821184 + dreg + 589824);  //     3,072

  hipMemsetAsync(stats, 0, 2 * C_ * sizeof(float), stream);
  k_cvt<<<3072, 256, 0, stream>>>(x, xhT, xlT);
  k_cvtw<<<144, 256, 0, stream>>>(Wg, WgH, WgL);
  k_sq1<<<1024, 256, 0, stream>>>(x, sqpart);
  k_sq2<<<64, 256, 0, stream>>>(sqpart, sq);
  for (int r = 0; r < B_ / nb; ++r) {
    k_gram<<<nb * 64, 256, 0, stream>>>(xhT, xlT, sq, Dbuf, r * nb, nb);
    k_scan<<<nb * 128, 256, 0, stream>>>(Dbuf, nbr, r * nb * N_);
  }
  k_xw<<<768, 256, 0, stream>>>(xhT, xlT, WgH, WgL, xw);
  k_agg<<<B_ * (C_ / 8), 256, 0, stream>>>(xw, nbr, bg, out, stats);
  k_bn<<<6144, 256, 0, stream>>>(x, gamma, beta, stats, out);
}